// Round 4
// baseline (627.337 us; speedup 1.0000x reference)
//
#include <hip/hip_runtime.h>

#define N_NODES  100000
#define N_EDGES  1600000
#define NODE_DIM 64
#define HID      32
#define NUM_LAYERS 3
#define SCAN_B   1024   // elements per scan1 block

// ---------------------------------------------------------------------------
template <int IN>
__device__ __forceinline__ void mlp2(const float (&in)[IN],
                                     const float* __restrict__ w1,
                                     const float* __restrict__ b1,
                                     const float* __restrict__ w2,
                                     const float* __restrict__ b2,
                                     float (&out)[HID]) {
    float h[HID];
#pragma unroll
    for (int j = 0; j < HID; ++j) h[j] = b1[j];
    for (int k = 0; k < IN; ++k) {
        float v = in[k];
#pragma unroll
        for (int j = 0; j < HID; ++j) h[j] = fmaf(v, w1[k * HID + j], h[j]);
    }
#pragma unroll
    for (int j = 0; j < HID; ++j) h[j] = fmaxf(h[j], 0.0f);
#pragma unroll
    for (int j = 0; j < HID; ++j) out[j] = b2[j];
    for (int k = 0; k < HID; ++k) {
        float v = h[k];
#pragma unroll
        for (int j = 0; j < HID; ++j) out[j] = fmaf(v, w2[k * HID + j], out[j]);
    }
}

__device__ __forceinline__ void load_row32(const float* __restrict__ p, float* dst) {
    const float4* p4 = reinterpret_cast<const float4*>(p);
#pragma unroll
    for (int k = 0; k < HID / 4; ++k) {
        float4 v = p4[k];
        dst[4 * k + 0] = v.x; dst[4 * k + 1] = v.y;
        dst[4 * k + 2] = v.z; dst[4 * k + 3] = v.w;
    }
}

__device__ __forceinline__ void store_row32(float* __restrict__ p, const float* src) {
    float4* p4 = reinterpret_cast<float4*>(p);
#pragma unroll
    for (int k = 0; k < HID / 4; ++k) {
        float4 v;
        v.x = src[4 * k + 0]; v.y = src[4 * k + 1];
        v.z = src[4 * k + 2]; v.w = src[4 * k + 3];
        p4[k] = v;
    }
}

// ------------------------------- sort: CSR by dst ---------------------------
__global__ void zero_int_kernel(int* __restrict__ p, int n) {
    int i = blockIdx.x * blockDim.x + threadIdx.x;
    if (i < n) p[i] = 0;
}

__global__ void rank_kernel(const int* __restrict__ ei,
                            int* __restrict__ cnt, int* __restrict__ rank) {
    int e = blockIdx.x * blockDim.x + threadIdx.x;
    if (e >= N_EDGES) return;
    int d = ei[N_EDGES + e];
    rank[e] = atomicAdd(&cnt[d], 1);
}

__global__ void scan1_kernel(const int* __restrict__ cnt, int* __restrict__ off,
                             int* __restrict__ bsum) {
    __shared__ int lds[256];
    int tid = threadIdx.x;
    int base = blockIdx.x * SCAN_B + tid * 4;
    int v0 = (base + 0 < N_NODES) ? cnt[base + 0] : 0;
    int v1 = (base + 1 < N_NODES) ? cnt[base + 1] : 0;
    int v2 = (base + 2 < N_NODES) ? cnt[base + 2] : 0;
    int v3 = (base + 3 < N_NODES) ? cnt[base + 3] : 0;
    int s1 = v0, s2 = v0 + v1, s3 = v0 + v1 + v2;
    int tsum = s3 + v3;
    lds[tid] = tsum;
    __syncthreads();
    for (int d = 1; d < 256; d <<= 1) {
        int t = lds[tid];
        int u = (tid >= d) ? lds[tid - d] : 0;
        __syncthreads();
        lds[tid] = t + u;
        __syncthreads();
    }
    int excl = lds[tid] - tsum;
    if (base + 0 < N_NODES) off[base + 0] = excl;
    if (base + 1 < N_NODES) off[base + 1] = excl + s1;
    if (base + 2 < N_NODES) off[base + 2] = excl + s2;
    if (base + 3 < N_NODES) off[base + 3] = excl + s3;
    if (tid == 255) bsum[blockIdx.x] = lds[255];
}

__global__ void scan2_kernel(const int* __restrict__ bsum, int* __restrict__ boff, int nb) {
    __shared__ int lds[256];
    int tid = threadIdx.x;
    int v = (tid < nb) ? bsum[tid] : 0;
    lds[tid] = v;
    __syncthreads();
    for (int d = 1; d < 256; d <<= 1) {
        int t = lds[tid];
        int u = (tid >= d) ? lds[tid - d] : 0;
        __syncthreads();
        lds[tid] = t + u;
        __syncthreads();
    }
    if (tid < nb) boff[tid] = lds[tid] - v;
}

__global__ void scan3_kernel(int* __restrict__ off, const int* __restrict__ boff) {
    int i = blockIdx.x * blockDim.x + threadIdx.x;
    if (i < N_NODES) off[i] += boff[i / SCAN_B];
}

// scatter: one 8B packed store per edge {src, dist_bits}
__global__ void scatter_kernel(const int* __restrict__ ei,
                               const float* __restrict__ pos,
                               const int* __restrict__ off,
                               const int* __restrict__ rank,
                               int2* __restrict__ edge_s) {
    int e = blockIdx.x * blockDim.x + threadIdx.x;
    if (e >= N_EDGES) return;
    int s = ei[e];
    int d = ei[N_EDGES + e];
    float dx = pos[d * 3 + 0] - pos[s * 3 + 0];
    float dy = pos[d * 3 + 1] - pos[s * 3 + 1];
    float dz = pos[d * 3 + 2] - pos[s * 3 + 2];
    float dist = sqrtf(dx * dx + dy * dy + dz * dz);
    int t = off[d] + rank[e];
    edge_s[t] = make_int2(s, __float_as_int(dist));
}

// ------------------------------- model kernels ------------------------------
__global__ void encoder_kernel(const float* __restrict__ feat,
                               const float* __restrict__ w1, const float* __restrict__ b1,
                               const float* __restrict__ w2, const float* __restrict__ b2,
                               float* __restrict__ xout) {
    int n = blockIdx.x * blockDim.x + threadIdx.x;
    if (n >= N_NODES) return;
    float f[NODE_DIM];
    const float4* fp = reinterpret_cast<const float4*>(feat + (size_t)n * NODE_DIM);
#pragma unroll
    for (int k = 0; k < NODE_DIM / 4; ++k) {
        float4 v = fp[k];
        f[4 * k + 0] = v.x; f[4 * k + 1] = v.y;
        f[4 * k + 2] = v.z; f[4 * k + 3] = v.w;
    }
    float y[HID];
    mlp2<NODE_DIM>(f, w1, b1, w2, b2, y);
    store_row32(xout + (size_t)n * HID, y);
}

// p = x @ W1[0:32] + b1 (dst half);  q = x @ W1[32:64] (src half)
__global__ void proj_kernel(const float* __restrict__ x,
                            const float* __restrict__ w1, const float* __restrict__ b1,
                            float* __restrict__ p, float* __restrict__ q) {
    int n = blockIdx.x * blockDim.x + threadIdx.x;
    if (n >= N_NODES) return;
    float xi[HID];
    load_row32(x + (size_t)n * HID, xi);
    float pp[HID], qq[HID];
#pragma unroll
    for (int j = 0; j < HID; ++j) { pp[j] = b1[j]; qq[j] = 0.0f; }
    for (int k = 0; k < HID; ++k) {
        float v = xi[k];
#pragma unroll
        for (int j = 0; j < HID; ++j) pp[j] = fmaf(v, w1[k * HID + j], pp[j]);
    }
    for (int k = 0; k < HID; ++k) {
        float v = xi[k];
#pragma unroll
        for (int j = 0; j < HID; ++j) qq[j] = fmaf(v, w1[(HID + k) * HID + j], qq[j]);
    }
    store_row32(p + (size_t)n * HID, pp);
    store_row32(q + (size_t)n * HID, qq);
}

// gather: 32 lanes per node, lane j owns hidden dim j. q-row reads coalesced.
// R may alias p (row n of p is only read/written by node n's own lane group).
__global__ __launch_bounds__(256) void gather_kernel(
        const float* __restrict__ p,
        const float* __restrict__ q,
        const int2* __restrict__ edge_s,
        const int* __restrict__ off,
        const float* __restrict__ wd,   // dist row of msg_w1 (row 64)
        float* __restrict__ R) {
    int slot = blockIdx.x * 8 + (threadIdx.x >> 5);
    int j = threadIdx.x & 31;
    if (slot >= N_NODES) return;
    int t0 = off[slot];
    int t1 = (slot == N_NODES - 1) ? N_EDGES : off[slot + 1];

    float pj  = p[(size_t)slot * HID + j];
    float wdj = wd[j];
    float rs0 = 0.0f, rs1 = 0.0f;

    int t = t0;
    for (; t + 2 <= t1; t += 2) {
        int2 e0 = edge_s[t];
        int2 e1 = edge_s[t + 1];
        float q0 = q[(size_t)e0.x * HID + j];
        float q1 = q[(size_t)e1.x * HID + j];
        float h0 = fmaf(__int_as_float(e0.y), wdj, pj + q0);
        float h1 = fmaf(__int_as_float(e1.y), wdj, pj + q1);
        rs0 += fmaxf(h0, 0.0f);
        rs1 += fmaxf(h1, 0.0f);
    }
    if (t < t1) {
        int2 e0 = edge_s[t];
        float q0 = q[(size_t)e0.x * HID + j];
        rs0 += fmaxf(fmaf(__int_as_float(e0.y), wdj, pj + q0), 0.0f);
    }
    R[(size_t)slot * HID + j] = rs0 + rs1;
}

// update: msg_out = R @ W2 + deg*b2 ; x = mlp2([x, msg_out], upd)  (in place)
__global__ void update_kernel(float* __restrict__ x,
                              const float* __restrict__ R,
                              const int* __restrict__ off,
                              const float* __restrict__ w2, const float* __restrict__ b2,
                              const float* __restrict__ uw1, const float* __restrict__ ub1,
                              const float* __restrict__ uw2, const float* __restrict__ ub2) {
    int n = blockIdx.x * blockDim.x + threadIdx.x;
    if (n >= N_NODES) return;
    int t0 = off[n];
    int t1 = (n == N_NODES - 1) ? N_EDGES : off[n + 1];
    float deg = (float)(t1 - t0);

    float rsum[HID];
    load_row32(R + (size_t)n * HID, rsum);
    float in[2 * HID];
    load_row32(x + (size_t)n * HID, in);
#pragma unroll
    for (int j = 0; j < HID; ++j) in[HID + j] = b2[j] * deg;
    for (int k = 0; k < HID; ++k) {
        float v = rsum[k];
#pragma unroll
        for (int j = 0; j < HID; ++j) in[HID + j] = fmaf(v, w2[k * HID + j], in[HID + j]);
    }
    float y[HID];
    mlp2<2 * HID>(in, uw1, ub1, uw2, ub2, y);
    store_row32(x + (size_t)n * HID, y);
}

__global__ void out_kernel(const float* __restrict__ x,
                           const float* __restrict__ w, const float* __restrict__ b,
                           float* __restrict__ out) {
    int n = blockIdx.x * blockDim.x + threadIdx.x;
    if (n >= N_NODES) return;
    float in[HID];
    load_row32(x + (size_t)n * HID, in);
    float y[HID];
#pragma unroll
    for (int j = 0; j < HID; ++j) y[j] = b[j];
    for (int k = 0; k < HID; ++k) {
        float v = in[k];
#pragma unroll
        for (int j = 0; j < HID; ++j) y[j] = fmaf(v, w[k * HID + j], y[j]);
    }
    store_row32(out + (size_t)n * HID, y);
}

// ---------------------------------------------------------------------------
extern "C" void kernel_launch(void* const* d_in, const int* in_sizes, int n_in,
                              void* d_out, int out_size, void* d_ws, size_t ws_size,
                              hipStream_t stream) {
    const float* node_feat = (const float*)d_in[0];
    const float* pos       = (const float*)d_in[1];
    const int*   ei        = (const int*)  d_in[2];
    const float* enc_w1    = (const float*)d_in[3];
    const float* enc_b1    = (const float*)d_in[4];
    const float* enc_w2    = (const float*)d_in[5];
    const float* enc_b2    = (const float*)d_in[6];
    const float* msg_w1    = (const float*)d_in[7];   // [3, 65, 32]
    const float* msg_b1    = (const float*)d_in[8];
    const float* msg_w2    = (const float*)d_in[9];   // [3, 32, 32]
    const float* msg_b2    = (const float*)d_in[10];
    const float* upd_w1    = (const float*)d_in[11];  // [3, 64, 32]
    const float* upd_b1    = (const float*)d_in[12];
    const float* upd_w2    = (const float*)d_in[13];
    const float* upd_b2    = (const float*)d_in[14];
    const float* out_w     = (const float*)d_in[15];
    const float* out_b     = (const float*)d_in[16];
    float* out = (float*)d_out;

    // workspace layout (bytes): edge_s[E*8] | x | p | q (12.8 MB each) |
    //                           rank[E*4] | cnt[N] | off[N+1] | bsum | boff
    char* ws = (char*)d_ws;
    int2*  edge_s = (int2*)ws;                                    // E * 8 B
    float* x      = (float*)(edge_s + N_EDGES);                   // N*32
    float* p      = x + (size_t)N_NODES * HID;                    // N*32
    float* q      = p + (size_t)N_NODES * HID;                    // N*32
    int*   rank   = (int*)(q + (size_t)N_NODES * HID);            // E
    int*   cnt    = rank + (size_t)N_EDGES;                       // N
    int*   off    = cnt + N_NODES;                                // N+1
    int*   bsum   = off + (N_NODES + 1);                          // <=256
    int*   boff   = bsum + 256;                                   // <=256
    float* R      = p;  // alias: gather consumes p row n before writing R row n

    const int B = 256;
    const int gridE = (N_EDGES + B - 1) / B;
    const int gridN = (N_NODES + B - 1) / B;
    const int gridG = (N_NODES + 7) / 8;          // 12500 blocks, 8 nodes/block
    const int NB = (N_NODES + SCAN_B - 1) / SCAN_B;

    // ---- build CSR (once per launch) ----
    zero_int_kernel<<<gridN, B, 0, stream>>>(cnt, N_NODES);
    rank_kernel<<<gridE, B, 0, stream>>>(ei, cnt, rank);
    scan1_kernel<<<NB, 256, 0, stream>>>(cnt, off, bsum);
    scan2_kernel<<<1, 256, 0, stream>>>(bsum, boff, NB);
    scan3_kernel<<<gridN, B, 0, stream>>>(off, boff);
    scatter_kernel<<<gridE, B, 0, stream>>>(ei, pos, off, rank, edge_s);

    // ---- model ----
    encoder_kernel<<<gridN, B, 0, stream>>>(node_feat, enc_w1, enc_b1, enc_w2, enc_b2, x);

    for (int l = 0; l < NUM_LAYERS; ++l) {
        const float* w1 = msg_w1 + (size_t)l * (2 * HID + 1) * HID;
        proj_kernel<<<gridN, B, 0, stream>>>(x, w1, msg_b1 + (size_t)l * HID, p, q);
        gather_kernel<<<gridG, B, 0, stream>>>(p, q, edge_s, off,
                                               w1 + 2 * HID * HID, R);
        update_kernel<<<gridN, B, 0, stream>>>(x, R, off,
                                               msg_w2 + (size_t)l * HID * HID,
                                               msg_b2 + (size_t)l * HID,
                                               upd_w1 + (size_t)l * (2 * HID) * HID,
                                               upd_b1 + (size_t)l * HID,
                                               upd_w2 + (size_t)l * HID * HID,
                                               upd_b2 + (size_t)l * HID);
    }
    out_kernel<<<gridN, B, 0, stream>>>(x, out_w, out_b, out);
}

// Round 5
// 558.826 us; speedup vs baseline: 1.1226x; 1.1226x over previous
//
#include <hip/hip_runtime.h>

#define N_NODES  100000
#define N_EDGES  1600000
#define NODE_DIM 64
#define HID      32
#define NUM_LAYERS 3
#define SCAN_B   1024

typedef unsigned int uint;
typedef unsigned short ushort;

// ---------------- bf16 helpers (RNE) ----------------
__device__ __forceinline__ ushort f2bf(float f) {
    uint u = __float_as_uint(f);
    uint r = (u + 0x7FFFu + ((u >> 16) & 1u)) >> 16;
    return (ushort)r;
}
__device__ __forceinline__ float bf2f(ushort s) {
    return __uint_as_float(((uint)s) << 16);
}
__device__ __forceinline__ uint pack2(float a, float b) {
    return (uint)f2bf(a) | ((uint)f2bf(b) << 16);
}

// ---------------------------------------------------------------------------
template <int IN>
__device__ __forceinline__ void mlp2(const float (&in)[IN],
                                     const float* __restrict__ w1,
                                     const float* __restrict__ b1,
                                     const float* __restrict__ w2,
                                     const float* __restrict__ b2,
                                     float (&out)[HID]) {
    float h[HID];
#pragma unroll
    for (int j = 0; j < HID; ++j) h[j] = b1[j];
    for (int k = 0; k < IN; ++k) {
        float v = in[k];
#pragma unroll
        for (int j = 0; j < HID; ++j) h[j] = fmaf(v, w1[k * HID + j], h[j]);
    }
#pragma unroll
    for (int j = 0; j < HID; ++j) h[j] = fmaxf(h[j], 0.0f);
#pragma unroll
    for (int j = 0; j < HID; ++j) out[j] = b2[j];
    for (int k = 0; k < HID; ++k) {
        float v = h[k];
#pragma unroll
        for (int j = 0; j < HID; ++j) out[j] = fmaf(v, w2[k * HID + j], out[j]);
    }
}

__device__ __forceinline__ void load_row32(const float* __restrict__ p, float* dst) {
    const float4* p4 = reinterpret_cast<const float4*>(p);
#pragma unroll
    for (int k = 0; k < HID / 4; ++k) {
        float4 v = p4[k];
        dst[4 * k + 0] = v.x; dst[4 * k + 1] = v.y;
        dst[4 * k + 2] = v.z; dst[4 * k + 3] = v.w;
    }
}

__device__ __forceinline__ void store_row32(float* __restrict__ p, const float* src) {
    float4* p4 = reinterpret_cast<float4*>(p);
#pragma unroll
    for (int k = 0; k < HID / 4; ++k) {
        float4 v;
        v.x = src[4 * k + 0]; v.y = src[4 * k + 1];
        v.z = src[4 * k + 2]; v.w = src[4 * k + 3];
        p4[k] = v;
    }
}

// ------------------------------- CSR build ---------------------------------
__global__ void zero_int_kernel(int* __restrict__ p, int n) {
    int i = blockIdx.x * blockDim.x + threadIdx.x;
    if (i < n) p[i] = 0;
}

__global__ void rank_kernel(const int* __restrict__ ei,
                            int* __restrict__ cnt, int* __restrict__ rank) {
    int e = blockIdx.x * blockDim.x + threadIdx.x;
    if (e >= N_EDGES) return;
    int d = ei[N_EDGES + e];
    rank[e] = atomicAdd(&cnt[d], 1);
}

// per-1024-chunk exclusive scan; off stays chunk-local, bsum = chunk totals
__global__ void scan1_kernel(const int* __restrict__ cnt, int* __restrict__ off,
                             int* __restrict__ bsum) {
    __shared__ int lds[256];
    int tid = threadIdx.x;
    int base = blockIdx.x * SCAN_B + tid * 4;
    int v0 = (base + 0 < N_NODES) ? cnt[base + 0] : 0;
    int v1 = (base + 1 < N_NODES) ? cnt[base + 1] : 0;
    int v2 = (base + 2 < N_NODES) ? cnt[base + 2] : 0;
    int v3 = (base + 3 < N_NODES) ? cnt[base + 3] : 0;
    int s1 = v0, s2 = v0 + v1, s3 = v0 + v1 + v2;
    int tsum = s3 + v3;
    lds[tid] = tsum;
    __syncthreads();
    for (int d = 1; d < 256; d <<= 1) {
        int t = lds[tid];
        int u = (tid >= d) ? lds[tid - d] : 0;
        __syncthreads();
        lds[tid] = t + u;
        __syncthreads();
    }
    int excl = lds[tid] - tsum;
    if (base + 0 < N_NODES) off[base + 0] = excl;
    if (base + 1 < N_NODES) off[base + 1] = excl + s1;
    if (base + 2 < N_NODES) off[base + 2] = excl + s2;
    if (base + 3 < N_NODES) off[base + 3] = excl + s3;
    if (tid == 255) bsum[blockIdx.x] = lds[255];
}

__global__ void scan2_kernel(const int* __restrict__ bsum, int* __restrict__ boff, int nb) {
    __shared__ int lds[256];
    int tid = threadIdx.x;
    int v = (tid < nb) ? bsum[tid] : 0;
    lds[tid] = v;
    __syncthreads();
    for (int d = 1; d < 256; d <<= 1) {
        int t = lds[tid];
        int u = (tid >= d) ? lds[tid - d] : 0;
        __syncthreads();
        lds[tid] = t + u;
        __syncthreads();
    }
    if (tid < nb) boff[tid] = lds[tid] - v;
}

// scatter: one 8B packed store per edge {src, dist_bits}; absolute off on the fly
__global__ void scatter_kernel(const int* __restrict__ ei,
                               const float* __restrict__ pos,
                               const int* __restrict__ off,
                               const int* __restrict__ boff,
                               const int* __restrict__ rank,
                               int2* __restrict__ edge_s) {
    int e = blockIdx.x * blockDim.x + threadIdx.x;
    if (e >= N_EDGES) return;
    int s = ei[e];
    int d = ei[N_EDGES + e];
    float dx = pos[d * 3 + 0] - pos[s * 3 + 0];
    float dy = pos[d * 3 + 1] - pos[s * 3 + 1];
    float dz = pos[d * 3 + 2] - pos[s * 3 + 2];
    float dist = sqrtf(dx * dx + dy * dy + dz * dz);
    int t = off[d] + boff[d >> 10] + rank[e];
    edge_s[t] = make_int2(s, __float_as_int(dist));
}

// ------------------------------- model kernels ------------------------------
// first=1: x = encoder(feat) computed inline and stored. Then p,q projections.
__global__ void proj_kernel(const float* __restrict__ feat,
                            float* __restrict__ x,
                            const float* __restrict__ ew1, const float* __restrict__ eb1,
                            const float* __restrict__ ew2, const float* __restrict__ eb2,
                            const float* __restrict__ w1, const float* __restrict__ b1,
                            float* __restrict__ p, ushort* __restrict__ qbf,
                            int first) {
    int n = blockIdx.x * blockDim.x + threadIdx.x;
    if (n >= N_NODES) return;
    float xi[HID];
    if (first) {
        float f[NODE_DIM];
        const float4* fp = reinterpret_cast<const float4*>(feat + (size_t)n * NODE_DIM);
#pragma unroll
        for (int k = 0; k < NODE_DIM / 4; ++k) {
            float4 v = fp[k];
            f[4 * k + 0] = v.x; f[4 * k + 1] = v.y;
            f[4 * k + 2] = v.z; f[4 * k + 3] = v.w;
        }
        mlp2<NODE_DIM>(f, ew1, eb1, ew2, eb2, xi);
        store_row32(x + (size_t)n * HID, xi);
    } else {
        load_row32(x + (size_t)n * HID, xi);
    }

    float pp[HID], qq[HID];
#pragma unroll
    for (int j = 0; j < HID; ++j) { pp[j] = b1[j]; qq[j] = 0.0f; }
    for (int k = 0; k < HID; ++k) {
        float v = xi[k];
#pragma unroll
        for (int j = 0; j < HID; ++j) pp[j] = fmaf(v, w1[k * HID + j], pp[j]);
    }
    for (int k = 0; k < HID; ++k) {
        float v = xi[k];
#pragma unroll
        for (int j = 0; j < HID; ++j) qq[j] = fmaf(v, w1[(HID + k) * HID + j], qq[j]);
    }
    store_row32(p + (size_t)n * HID, pp);
    uint4* qp = reinterpret_cast<uint4*>(qbf + (size_t)n * HID);
#pragma unroll
    for (int k = 0; k < 4; ++k) {
        uint4 u;
        u.x = pack2(qq[8 * k + 0], qq[8 * k + 1]);
        u.y = pack2(qq[8 * k + 2], qq[8 * k + 3]);
        u.z = pack2(qq[8 * k + 4], qq[8 * k + 5]);
        u.w = pack2(qq[8 * k + 6], qq[8 * k + 7]);
        qp[k] = u;
    }
}

// fused gather + msg@W2 + update MLP (+ optional final output head).
// 32 lanes per node (lane j owns dim j); per-node broadcasts via __shfl width 32
// (a node's lanes sit in one half-wave -> no LDS, no __syncthreads needed).
__global__ __launch_bounds__(256) void gu_kernel(
        float* __restrict__ x,
        const float* __restrict__ p,
        const ushort* __restrict__ qbf,
        const int2* __restrict__ edge_s,
        const int* __restrict__ off,
        const int* __restrict__ boff,
        const float* __restrict__ wd,   // dist row (row 64) of msg_w1
        const float* __restrict__ w2,  const float* __restrict__ b2,
        const float* __restrict__ uw1, const float* __restrict__ ub1,
        const float* __restrict__ uw2, const float* __restrict__ ub2,
        const float* __restrict__ ow,  const float* __restrict__ ob,
        float* __restrict__ out, int final) {
    int g = threadIdx.x >> 5;
    int j = threadIdx.x & 31;
    int n = blockIdx.x * 8 + g;          // N_NODES = 12500*8 exactly
    int t0 = off[n] + boff[n >> 10];
    int t1 = (n == N_NODES - 1) ? N_EDGES : off[n + 1] + boff[(n + 1) >> 10];

    float pj  = p[(size_t)n * HID + j];
    float wdj = wd[j];
    float rs0 = 0.0f, rs1 = 0.0f;
    int t = t0;
    for (; t + 2 <= t1; t += 2) {
        int2 e0 = edge_s[t];
        int2 e1 = edge_s[t + 1];
        float q0 = bf2f(qbf[(size_t)e0.x * HID + j]);
        float q1 = bf2f(qbf[(size_t)e1.x * HID + j]);
        float h0 = fmaf(__int_as_float(e0.y), wdj, pj + q0);
        float h1 = fmaf(__int_as_float(e1.y), wdj, pj + q1);
        rs0 += fmaxf(h0, 0.0f);
        rs1 += fmaxf(h1, 0.0f);
    }
    if (t < t1) {
        int2 e0 = edge_s[t];
        float q0 = bf2f(qbf[(size_t)e0.x * HID + j]);
        rs0 += fmaxf(fmaf(__int_as_float(e0.y), wdj, pj + q0), 0.0f);
    }
    float rsum = rs0 + rs1;
    float deg = (float)(t1 - t0);

    // msg[j] = deg*b2[j] + sum_k rsum[k] * w2[k][j]
    float msg = deg * b2[j];
#pragma unroll
    for (int k = 0; k < HID; ++k)
        msg = fmaf(__shfl(rsum, k, 32), w2[k * HID + j], msg);

    // h[j] = relu(ub1[j] + sum_k x[k]*uw1[k][j] + sum_k msg[k]*uw1[32+k][j])
    float xj = x[(size_t)n * HID + j];
    float h = ub1[j];
#pragma unroll
    for (int k = 0; k < HID; ++k)
        h = fmaf(__shfl(xj, k, 32), uw1[k * HID + j], h);
#pragma unroll
    for (int k = 0; k < HID; ++k)
        h = fmaf(__shfl(msg, k, 32), uw1[(HID + k) * HID + j], h);
    h = fmaxf(h, 0.0f);

    // y[j] = ub2[j] + sum_k h[k]*uw2[k][j]
    float y = ub2[j];
#pragma unroll
    for (int k = 0; k < HID; ++k)
        y = fmaf(__shfl(h, k, 32), uw2[k * HID + j], y);
    x[(size_t)n * HID + j] = y;

    if (final) {
        float o = ob[j];
#pragma unroll
        for (int k = 0; k < HID; ++k)
            o = fmaf(__shfl(y, k, 32), ow[k * HID + j], o);
        out[(size_t)n * HID + j] = o;
    }
}

// ---------------------------------------------------------------------------
extern "C" void kernel_launch(void* const* d_in, const int* in_sizes, int n_in,
                              void* d_out, int out_size, void* d_ws, size_t ws_size,
                              hipStream_t stream) {
    const float* node_feat = (const float*)d_in[0];
    const float* pos       = (const float*)d_in[1];
    const int*   ei        = (const int*)  d_in[2];
    const float* enc_w1    = (const float*)d_in[3];
    const float* enc_b1    = (const float*)d_in[4];
    const float* enc_w2    = (const float*)d_in[5];
    const float* enc_b2    = (const float*)d_in[6];
    const float* msg_w1    = (const float*)d_in[7];   // [3, 65, 32]
    const float* msg_b1    = (const float*)d_in[8];
    const float* msg_w2    = (const float*)d_in[9];   // [3, 32, 32]
    const float* msg_b2    = (const float*)d_in[10];
    const float* upd_w1    = (const float*)d_in[11];  // [3, 64, 32]
    const float* upd_b1    = (const float*)d_in[12];
    const float* upd_w2    = (const float*)d_in[13];
    const float* upd_b2    = (const float*)d_in[14];
    const float* out_w     = (const float*)d_in[15];
    const float* out_b     = (const float*)d_in[16];
    float* out = (float*)d_out;

    // workspace: edge_s 12.8 | x 12.8 | p 12.8 | qbf 6.4 | rank 6.4 | cnt/off/bsum/boff  ~51.6 MB
    char* ws = (char*)d_ws;
    int2*   edge_s = (int2*)ws;                                   // E
    float*  x      = (float*)(edge_s + N_EDGES);                  // N*32
    float*  p      = x + (size_t)N_NODES * HID;                   // N*32
    ushort* qbf    = (ushort*)(p + (size_t)N_NODES * HID);        // N*32 bf16
    int*    rank   = (int*)(qbf + (size_t)N_NODES * HID);         // E
    int*    cnt    = rank + (size_t)N_EDGES;                      // N
    int*    off    = cnt + N_NODES;                               // N+1
    int*    bsum   = off + (N_NODES + 1);                         // <=128
    int*    boff   = bsum + 128;                                  // <=128

    const int B = 256;
    const int gridE = (N_EDGES + B - 1) / B;
    const int gridN = (N_NODES + B - 1) / B;
    const int gridG = N_NODES / 8;                 // 12500 (exact)
    const int NB = (N_NODES + SCAN_B - 1) / SCAN_B; // 98

    // ---- CSR build ----
    zero_int_kernel<<<gridN, B, 0, stream>>>(cnt, N_NODES);
    rank_kernel<<<gridE, B, 0, stream>>>(ei, cnt, rank);
    scan1_kernel<<<NB, 256, 0, stream>>>(cnt, off, bsum);
    scan2_kernel<<<1, 256, 0, stream>>>(bsum, boff, NB);
    scatter_kernel<<<gridE, B, 0, stream>>>(ei, pos, off, boff, rank, edge_s);

    // ---- model: [proj, gather+update] x3, encoder/out head fused in ----
    for (int l = 0; l < NUM_LAYERS; ++l) {
        const float* w1 = msg_w1 + (size_t)l * (2 * HID + 1) * HID;
        proj_kernel<<<gridN, B, 0, stream>>>(node_feat, x,
                                             enc_w1, enc_b1, enc_w2, enc_b2,
                                             w1, msg_b1 + (size_t)l * HID,
                                             p, qbf, l == 0 ? 1 : 0);
        gu_kernel<<<gridG, B, 0, stream>>>(x, p, qbf, edge_s, off, boff,
                                           w1 + 2 * HID * HID,
                                           msg_w2 + (size_t)l * HID * HID,
                                           msg_b2 + (size_t)l * HID,
                                           upd_w1 + (size_t)l * (2 * HID) * HID,
                                           upd_b1 + (size_t)l * HID,
                                           upd_w2 + (size_t)l * HID * HID,
                                           upd_b2 + (size_t)l * HID,
                                           out_w, out_b, out,
                                           l == NUM_LAYERS - 1 ? 1 : 0);
    }
}